// Round 7
// baseline (42.397 us; speedup 1.0000x reference)
//
#include <hip/hip_runtime.h>
#include <stdint.h>

#define DIM_IN  4096
#define DIM_OUT 4096
#define BATCH   64
// words along dim_in: 4096/64 = 64

typedef unsigned long long u64;
typedef uint32_t u32;

// ---------------------------------------------------------------------------
// Input-format detection (first 8 u32 words):
//   int32 0/1 or float 0.0/1.0 -> "word" layout (4B per bool)
//   uint8 0/1                  -> "byte" layout (1B per bool)
// Rounds 3-6: FETCH ~33.4 MB (> byte-ideal 16.7 MB) pins the encoding as
// words. Byte path kept for robustness (misclassify P ~ 2^-192).
// ---------------------------------------------------------------------------
__device__ __forceinline__ bool is_word_fmt(const u32* __restrict__ p) {
    bool words = true;
#pragma unroll
    for (int i = 0; i < 8; ++i) {
        u32 v = p[i];
        if (v > 1u && v != 0x3F800000u) words = false;
    }
    return words;
}

// ---------------------------------------------------------------------------
// K1 (fused pack), 528 blocks x 256 threads.
//
// blocks 0..511: mask pack, contiguous-chunk + line-clean stores.
//   Block b: w = b>>3 (row-group), oseg = b&7 (512-col segment).
//   Thread t owns 2 adjacent columns o = oseg*512 + t*2 {+0,+1}.
//   Per row the BLOCK reads a contiguous 2 KB chunk (256 thr x uint2);
//   per wave 512 B contiguous. 64 rows in 8 batches of 8 staged loads
//   (8 x 8B in flight per wave). All shift amounts compile-time.
//   Stores: block owns mp[w][oseg*512 .. +511] = 4 KB exclusive -> no
//   cross-block 64B-line sharing (round-5 disease avoided).
//
// blocks 512..527: x pack via wave ballot (64 waves x 64 words).
// ---------------------------------------------------------------------------
__global__ __launch_bounds__(256) void pack_kernel(
        const void* __restrict__ masks, const void* __restrict__ x,
        u64* __restrict__ mp, u64* __restrict__ xp) {
    const int bid = blockIdx.x;
    if (bid < 512) {
        const bool words = is_word_fmt((const u32*)masks);
        const int w    = bid >> 3;                       // 0..63
        const int oseg = bid & 7;                        // 0..7
        const int o    = oseg * 512 + threadIdx.x * 2;   // 2 adjacent columns
        const int row0 = w * 64;

        u32 lo0 = 0, lo1 = 0, hi0 = 0, hi1 = 0;

        if (words) {
            const u32* base = (const u32*)masks + (size_t)row0 * DIM_OUT + o;
#pragma unroll
            for (int rb = 0; rb < 8; ++rb) {
                uint2 v[8];
#pragma unroll
                for (int r = 0; r < 8; ++r)
                    v[r] = *reinterpret_cast<const uint2*>(
                               base + (size_t)(rb * 8 + r) * DIM_OUT);
#pragma unroll
                for (int r = 0; r < 8; ++r) {
                    const int row = rb * 8 + r;          // compile-time
                    if (row < 32) {
                        lo0 |= (u32)(v[r].x != 0u) << row;
                        lo1 |= (u32)(v[r].y != 0u) << row;
                    } else {
                        hi0 |= (u32)(v[r].x != 0u) << (row - 32);
                        hi1 |= (u32)(v[r].y != 0u) << (row - 32);
                    }
                }
            }
        } else {
            const uint8_t* base = (const uint8_t*)masks + (size_t)row0 * DIM_OUT + o;
#pragma unroll
            for (int rb = 0; rb < 8; ++rb) {
                ushort v[8];
#pragma unroll
                for (int r = 0; r < 8; ++r)
                    v[r] = *reinterpret_cast<const ushort*>(
                               base + (size_t)(rb * 8 + r) * DIM_OUT);
#pragma unroll
                for (int r = 0; r < 8; ++r) {
                    const int row = rb * 8 + r;
                    if (row < 32) {
                        lo0 |= (u32)((v[r] & 0x00FFu) != 0u) << row;
                        lo1 |= (u32)((v[r] & 0xFF00u) != 0u) << row;
                    } else {
                        hi0 |= (u32)((v[r] & 0x00FFu) != 0u) << (row - 32);
                        hi1 |= (u32)((v[r] & 0xFF00u) != 0u) << (row - 32);
                    }
                }
            }
        }

        u64* dst = mp + (size_t)w * DIM_OUT + o;
        dst[0] = (u64)lo0 | ((u64)hi0 << 32);
        dst[1] = (u64)lo1 | ((u64)hi1 << 32);
    } else {
        // ------------------- x pack -------------------
        const bool words = is_word_fmt((const u32*)x);
        const int bxid = bid - 512;                           // 0..15
        const int wave = bxid * 4 + (threadIdx.x >> 6);       // 0..63
        const int lane = threadIdx.x & 63;
        const int base = wave * 64;                           // word index base

#pragma unroll 16
        for (int k = 0; k < 64; ++k) {
            const int idx = base + k;                         // 0..4095
            const size_t e = (size_t)idx * 64 + lane;         // element index
            bool pred;
            if (words) pred = ((const u32*)x)[e] != 0u;
            else       pred = ((const uint8_t*)x)[e] != 0u;
            const u64 m = __ballot(pred);
            if (lane == 0) xp[idx] = m;
        }
    }
}

// ---------------------------------------------------------------------------
// K2: out[b][o] = ((4096 - sum_w popc(xp[b][w] ^ mp[w][o])) > thr[o]) ? 1 : 0
// Output dtype INT32 (bool output -> int32 harness path).
// Grid: (16 o-blocks, 16 b-blocks) x 256 threads; 4 batch rows per thread.
// ---------------------------------------------------------------------------
__global__ __launch_bounds__(256) void bnn_kernel(
        const u64* __restrict__ mp, const u64* __restrict__ xp,
        const int* __restrict__ thr, int* __restrict__ out) {
    const int o  = blockIdx.x * 256 + threadIdx.x;
    const int b0 = blockIdx.y * 4;

    const u64* __restrict__ x0 = xp + (size_t)(b0 + 0) * 64;
    const u64* __restrict__ x1 = xp + (size_t)(b0 + 1) * 64;
    const u64* __restrict__ x2 = xp + (size_t)(b0 + 2) * 64;
    const u64* __restrict__ x3 = xp + (size_t)(b0 + 3) * 64;

    int a0 = 0, a1 = 0, a2 = 0, a3 = 0;
#pragma unroll 16
    for (int w = 0; w < 64; ++w) {
        const u64 mw = mp[(size_t)w * DIM_OUT + o];
        a0 += __popcll(x0[w] ^ mw);
        a1 += __popcll(x1[w] ^ mw);
        a2 += __popcll(x2[w] ^ mw);
        a3 += __popcll(x3[w] ^ mw);
    }

    const int t = thr[o];
    out[(size_t)(b0 + 0) * DIM_OUT + o] = (DIM_IN - a0) > t ? 1 : 0;
    out[(size_t)(b0 + 1) * DIM_OUT + o] = (DIM_IN - a1) > t ? 1 : 0;
    out[(size_t)(b0 + 2) * DIM_OUT + o] = (DIM_IN - a2) > t ? 1 : 0;
    out[(size_t)(b0 + 3) * DIM_OUT + o] = (DIM_IN - a3) > t ? 1 : 0;
}

// ---------------------------------------------------------------------------
extern "C" void kernel_launch(void* const* d_in, const int* in_sizes, int n_in,
                              void* d_out, int out_size, void* d_ws, size_t ws_size,
                              hipStream_t stream) {
    const void* x     = d_in[0];                 // bool [64][4096]
    const void* masks = d_in[1];                 // bool [4096][4096]
    const int*  thr   = (const int*)d_in[2];     // int32 [4096]
    int* out = (int*)d_out;                      // [64][4096] int32 0/1

    u64* mp = (u64*)d_ws;                                        // 2 MiB
    u64* xp = (u64*)((char*)d_ws + (size_t)64 * DIM_OUT * 8);    // 32 KiB

    pack_kernel<<<dim3(528), dim3(256), 0, stream>>>(masks, x, mp, xp);
    bnn_kernel<<<dim3(16, 16), dim3(256), 0, stream>>>(mp, xp, thr, out);
}

// Round 8
// 38.053 us; speedup vs baseline: 1.1141x; 1.1141x over previous
//
#include <hip/hip_runtime.h>
#include <stdint.h>

#define DIM_IN  4096
#define DIM_OUT 4096
#define BATCH   64
// words along dim_in: 4096/64 = 64

typedef unsigned long long u64;
typedef uint32_t u32;

// ---------------------------------------------------------------------------
// Input-format detection (first 8 u32 words):
//   int32 0/1 or float 0.0/1.0 -> "word" layout (4B per bool)
//   uint8 0/1                  -> "byte" layout (1B per bool)
// Rounds 3-7: FETCH ~33.4 MB (= half of the 67 MB word-encoded masks, L2
// retains the other half) pins the encoding as words. Byte path kept for
// robustness (misclassify P ~ 2^-192). Uniform addresses -> scalar loads.
// ---------------------------------------------------------------------------
__device__ __forceinline__ bool is_word_fmt(const u32* __restrict__ p) {
    bool words = true;
#pragma unroll
    for (int i = 0; i < 8; ++i) {
        u32 v = p[i];
        if (v > 1u && v != 0x3F800000u) words = false;
    }
    return words;
}

// ---------------------------------------------------------------------------
// K1 (fused pack), 272 blocks x 256 threads.
//
// blocks 0..255: mask pack, WIDE loads (16 B/lane) to maximize bytes in
//   flight per outstanding VMEM instruction (rounds 3-7 showed the L2-miss
//   stream pinned at ~0.7 TB/s with 4-8 B/lane loads regardless of pattern).
//   Block b: w = b>>2 (row-group), oseg = b&3 (1024-col segment).
//   Thread t owns 4 adjacent columns o = oseg*1024 + t*4.
//   Per row the block reads a contiguous 4 KB chunk (256 thr x uint4);
//   64 rows in 8 batches of 8 staged uint4 loads (128 B in flight/lane).
//   Bit-slices accumulate in registers (no transpose); stores are 4
//   contiguous u64 per thread (32 B), 8 KB exclusive per block.
//
// blocks 256..271: x pack via wave ballot (64 waves x 64 words).
// ---------------------------------------------------------------------------
__global__ __launch_bounds__(256) void pack_kernel(
        const void* __restrict__ masks, const void* __restrict__ x,
        u64* __restrict__ mp, u64* __restrict__ xp) {
    const int bid = blockIdx.x;
    if (bid < 256) {
        const bool words = is_word_fmt((const u32*)masks);
        const int w    = bid >> 2;                        // 0..63
        const int oseg = bid & 3;                         // 0..3
        const int o0   = oseg * 1024 + threadIdx.x * 4;   // 4 adjacent columns
        const int row0 = w * 64;

        u32 lo[4] = {0u, 0u, 0u, 0u};
        u32 hi[4] = {0u, 0u, 0u, 0u};

        if (words) {
            const u32* base = (const u32*)masks + (size_t)row0 * DIM_OUT + o0;
#pragma unroll
            for (int rb = 0; rb < 8; ++rb) {
                uint4 v[8];
#pragma unroll
                for (int r = 0; r < 8; ++r)
                    v[r] = *reinterpret_cast<const uint4*>(
                               base + (size_t)(rb * 8 + r) * DIM_OUT);
#pragma unroll
                for (int r = 0; r < 8; ++r) {
                    const int row = rb * 8 + r;           // compile-time
                    if (row < 32) {
                        lo[0] |= (u32)(v[r].x != 0u) << row;
                        lo[1] |= (u32)(v[r].y != 0u) << row;
                        lo[2] |= (u32)(v[r].z != 0u) << row;
                        lo[3] |= (u32)(v[r].w != 0u) << row;
                    } else {
                        hi[0] |= (u32)(v[r].x != 0u) << (row - 32);
                        hi[1] |= (u32)(v[r].y != 0u) << (row - 32);
                        hi[2] |= (u32)(v[r].z != 0u) << (row - 32);
                        hi[3] |= (u32)(v[r].w != 0u) << (row - 32);
                    }
                }
            }
        } else {
            // byte layout: thread's 4 columns = one u32 per row.
            const u32* base = (const u32*)((const uint8_t*)masks
                                + (size_t)row0 * DIM_OUT + o0);
#pragma unroll
            for (int rb = 0; rb < 8; ++rb) {
                u32 v[8];
#pragma unroll
                for (int r = 0; r < 8; ++r)
                    v[r] = base[(size_t)(rb * 8 + r) * (DIM_OUT / 4)];
#pragma unroll
                for (int r = 0; r < 8; ++r) {
                    const int row = rb * 8 + r;
                    if (row < 32) {
                        lo[0] |= (u32)((v[r] & 0x000000FFu) != 0u) << row;
                        lo[1] |= (u32)((v[r] & 0x0000FF00u) != 0u) << row;
                        lo[2] |= (u32)((v[r] & 0x00FF0000u) != 0u) << row;
                        lo[3] |= (u32)((v[r] & 0xFF000000u) != 0u) << row;
                    } else {
                        hi[0] |= (u32)((v[r] & 0x000000FFu) != 0u) << (row - 32);
                        hi[1] |= (u32)((v[r] & 0x0000FF00u) != 0u) << (row - 32);
                        hi[2] |= (u32)((v[r] & 0x00FF0000u) != 0u) << (row - 32);
                        hi[3] |= (u32)((v[r] & 0xFF000000u) != 0u) << (row - 32);
                    }
                }
            }
        }

        u64* dst = mp + (size_t)w * DIM_OUT + o0;
#pragma unroll
        for (int c = 0; c < 4; ++c)
            dst[c] = (u64)lo[c] | ((u64)hi[c] << 32);
    } else {
        // ------------------- x pack -------------------
        const bool words = is_word_fmt((const u32*)x);
        const int bxid = bid - 256;                           // 0..15
        const int wave = bxid * 4 + (threadIdx.x >> 6);       // 0..63
        const int lane = threadIdx.x & 63;
        const int base = wave * 64;                           // word index base

#pragma unroll 16
        for (int k = 0; k < 64; ++k) {
            const int idx = base + k;                         // 0..4095
            const size_t e = (size_t)idx * 64 + lane;         // element index
            bool pred;
            if (words) pred = ((const u32*)x)[e] != 0u;
            else       pred = ((const uint8_t*)x)[e] != 0u;
            const u64 m = __ballot(pred);
            if (lane == 0) xp[idx] = m;
        }
    }
}

// ---------------------------------------------------------------------------
// K2: out[b][o] = ((4096 - sum_w popc(xp[b][w] ^ mp[w][o])) > thr[o]) ? 1 : 0
// Output dtype INT32 (bool output -> int32 harness path).
// Grid: (16 o-blocks, 16 b-blocks) x 256 threads; 4 batch rows per thread.
// ---------------------------------------------------------------------------
__global__ __launch_bounds__(256) void bnn_kernel(
        const u64* __restrict__ mp, const u64* __restrict__ xp,
        const int* __restrict__ thr, int* __restrict__ out) {
    const int o  = blockIdx.x * 256 + threadIdx.x;
    const int b0 = blockIdx.y * 4;

    const u64* __restrict__ x0 = xp + (size_t)(b0 + 0) * 64;
    const u64* __restrict__ x1 = xp + (size_t)(b0 + 1) * 64;
    const u64* __restrict__ x2 = xp + (size_t)(b0 + 2) * 64;
    const u64* __restrict__ x3 = xp + (size_t)(b0 + 3) * 64;

    int a0 = 0, a1 = 0, a2 = 0, a3 = 0;
#pragma unroll 16
    for (int w = 0; w < 64; ++w) {
        const u64 mw = mp[(size_t)w * DIM_OUT + o];
        a0 += __popcll(x0[w] ^ mw);
        a1 += __popcll(x1[w] ^ mw);
        a2 += __popcll(x2[w] ^ mw);
        a3 += __popcll(x3[w] ^ mw);
    }

    const int t = thr[o];
    out[(size_t)(b0 + 0) * DIM_OUT + o] = (DIM_IN - a0) > t ? 1 : 0;
    out[(size_t)(b0 + 1) * DIM_OUT + o] = (DIM_IN - a1) > t ? 1 : 0;
    out[(size_t)(b0 + 2) * DIM_OUT + o] = (DIM_IN - a2) > t ? 1 : 0;
    out[(size_t)(b0 + 3) * DIM_OUT + o] = (DIM_IN - a3) > t ? 1 : 0;
}

// ---------------------------------------------------------------------------
extern "C" void kernel_launch(void* const* d_in, const int* in_sizes, int n_in,
                              void* d_out, int out_size, void* d_ws, size_t ws_size,
                              hipStream_t stream) {
    const void* x     = d_in[0];                 // bool [64][4096]
    const void* masks = d_in[1];                 // bool [4096][4096]
    const int*  thr   = (const int*)d_in[2];     // int32 [4096]
    int* out = (int*)d_out;                      // [64][4096] int32 0/1

    u64* mp = (u64*)d_ws;                                        // 2 MiB
    u64* xp = (u64*)((char*)d_ws + (size_t)64 * DIM_OUT * 8);    // 32 KiB

    pack_kernel<<<dim3(272), dim3(256), 0, stream>>>(masks, x, mp, xp);
    bnn_kernel<<<dim3(16, 16), dim3(256), 0, stream>>>(mp, xp, thr, out);
}